// Round 1
// baseline (211662.109 us; speedup 1.0000x reference)
//
#include <hip/hip_runtime.h>
#include <cstddef>

#define LRC 0.001f
#define DEC 0.99f
#define NBLK 256

// ---------------- workspace layout (float offsets) ----------------
static const size_t OFF_Z1P = 0;            // [32][2048]
static const size_t OFF_Z2P = 65536;        // [32][2048]
static const size_t OFF_Z2Q = 131072;
static const size_t OFF_Z3P = 196608;
static const size_t OFF_Z3Q = 262144;
static const size_t OFF_Z4P = 327680;       // [32][768]
static const size_t OFF_Z4Q = 352256;
static const size_t OFF_H1F = 376832;       // 2048 each below
static const size_t OFF_H1Q = 378880;
static const size_t OFF_H2F = 380928;
static const size_t OFF_H2Q = 382976;
static const size_t OFF_H3F = 385024;
static const size_t OFF_H3Q = 387072;
static const size_t OFF_D4F = 389120;       // 768
static const size_t OFF_D4Q = 389888;       // 768
static const size_t OFF_D3F = 390656;       // 2048
static const size_t OFF_D3Q = 392704;
static const size_t OFF_D2F = 394752;
static const size_t OFF_D2Q = 396800;
static const size_t OFF_D1F = 398848;
static const size_t OFF_D1Q = 400896;
static const size_t OFF_NSQ = 402944;       // 16: 0=x,1=h1,2=h2,3=h3,4=d4
static const size_t OFF_SL3 = 402960;       // 256 per-block |d3|^2 partials
static const size_t OFF_SL2 = 403216;
static const size_t OFF_SL1 = 403472;
static const size_t OFF_BUF = 403728;       // 2 (ping-pong EMA buffer)
static const size_t OFF_CONDF = 403730;     // 1 (cond flag for current step's fused update)
static const size_t OFF_MSUM = 403732;      // [32][768]
static const size_t OFF_HA  = 428308;       // 1024*2048  (first 4KB double as barrier state during scan)
static const size_t OFF_HB  = 2525460;      // 1024*2048

__device__ __forceinline__ void fma4(float4& a, float s, const float4& w) {
    a.x += s * w.x; a.y += s * w.y; a.z += s * w.z; a.w += s * w.w;
}

__device__ __forceinline__ float block_reduce_512s(float v, float* red) {
    int t = threadIdx.x;
    red[t] = v;
    __syncthreads();
    for (int st = 256; st > 0; st >>= 1) {
        if (t < st) red[t] += red[t + st];
        __syncthreads();
    }
    float r = red[0];
    __syncthreads();
    return r;
}

// ---- grid barrier: two-level generation barrier over 256 co-resident blocks ----
// layout (unsigned idx at bar): gen@0, root@32, grp[i]@64+32*i (i<16)
__device__ __forceinline__ void gbar(unsigned* bar) {
    __syncthreads();
    if (threadIdx.x == 0) {
        __threadfence();   // push this XCD's dirty L2 lines to the coherence point
        unsigned g = __hip_atomic_load(bar, __ATOMIC_RELAXED, __HIP_MEMORY_SCOPE_AGENT);
        unsigned* grp = bar + 64 + ((blockIdx.x >> 4) << 5);
        if (__hip_atomic_fetch_add(grp, 1u, __ATOMIC_ACQ_REL, __HIP_MEMORY_SCOPE_AGENT) == 15u) {
            if (__hip_atomic_fetch_add(bar + 32, 1u, __ATOMIC_ACQ_REL, __HIP_MEMORY_SCOPE_AGENT) == 15u) {
#pragma unroll
                for (int i = 0; i < 16; ++i)
                    __hip_atomic_store(bar + 64 + (i << 5), 0u, __ATOMIC_RELAXED, __HIP_MEMORY_SCOPE_AGENT);
                __hip_atomic_store(bar + 32, 0u, __ATOMIC_RELAXED, __HIP_MEMORY_SCOPE_AGENT);
                __hip_atomic_store(bar, g + 1u, __ATOMIC_RELEASE, __HIP_MEMORY_SCOPE_AGENT);
            }
        }
        while (__hip_atomic_load(bar, __ATOMIC_RELAXED, __HIP_MEMORY_SCOPE_AGENT) == g)
            __builtin_amdgcn_s_sleep(2);
        __threadfence();   // acquire: invalidate stale L1/L2 before reading remote writes
    }
    __syncthreads();
}

// ---------- phase A: fused [apply step-(s-1) W1/b1 update] + z1 partials ----------
__device__ __forceinline__ void ph_fwd1(int step,
                                        const float* __restrict__ xt,
                                        const float* __restrict__ xprev,
                                        float* __restrict__ W1,
                                        float* __restrict__ b1,
                                        float* __restrict__ wsf,
                                        float* smem) {
    int b = blockIdx.x;
    int g = b >> 5, p = b & 31;
    int tid = threadIdx.x, w = tid >> 6, lane = tid & 63;
    int c0 = g * 256 + lane * 4;
    int kb = p * 24 + w * 3;

    float4 wv0 = *(const float4*)(W1 + (size_t)(kb + 0) * 2048 + c0);
    float4 wv1 = *(const float4*)(W1 + (size_t)(kb + 1) * 2048 + c0);
    float4 wv2 = *(const float4*)(W1 + (size_t)(kb + 2) * 2048 + c0);
    float a0 = xt[kb + 0], a1 = xt[kb + 1], a2 = xt[kb + 2];
    float4 dv = make_float4(0.f, 0.f, 0.f, 0.f);
    float u0 = 0.f, u1 = 0.f, u2 = 0.f;
    if (step > 0) {
        dv = *(const float4*)(wsf + OFF_D1Q + c0);
        u0 = LRC * xprev[kb + 0]; u1 = LRC * xprev[kb + 1]; u2 = LRC * xprev[kb + 2];
    }

    float* cnd = smem + 2048;
    float cond = 0.f;
    if (step > 0) {
        if (w < 3) {
            const float* sl = wsf + (w == 0 ? OFF_SL1 : (w == 1 ? OFF_SL2 : OFF_SL3));
            float v = sl[lane] + sl[lane + 64] + sl[lane + 128] + sl[lane + 192];
#pragma unroll
            for (int off = 32; off > 0; off >>= 1) v += __shfl_down(v, off);
            if (lane == 0) cnd[w] = v;
        }
        __syncthreads();
        float nd1 = sqrtf(cnd[0]), nd2 = sqrtf(cnd[1]), nd3 = sqrtf(cnd[2]);
        float nx = sqrtf(wsf[OFF_NSQ + 0]);
        float nh1 = sqrtf(wsf[OFF_NSQ + 1]);
        float nh2 = sqrtf(wsf[OFF_NSQ + 2]);
        float nh3 = sqrtf(wsf[OFF_NSQ + 3]);
        float nd4 = sqrtf(wsf[OFF_NSQ + 4]);
        float surprise = nx * nd1 + nd1 + nh1 * nd2 + nd2 + nh2 * nd3 + nd3 + nh3 * nd4 + nd4;
        float bufold = wsf[OFF_BUF + ((step - 1) & 1)];
        float bufnew = (step == 1) ? surprise : (0.9f * bufold + 0.1f * surprise);
        cond = (bufnew > 0.1f) ? 1.f : 0.f;
        if (b == 0 && tid == 0) {
            wsf[OFF_BUF + (step & 1)] = bufnew;
            wsf[OFF_CONDF] = cond;
        }
    } else {
        if (b == 0 && tid == 0) wsf[OFF_CONDF] = 0.f;
    }

    if (cond != 0.f) {
        wv0.x = DEC * wv0.x - u0 * dv.x; wv0.y = DEC * wv0.y - u0 * dv.y;
        wv0.z = DEC * wv0.z - u0 * dv.z; wv0.w = DEC * wv0.w - u0 * dv.w;
        wv1.x = DEC * wv1.x - u1 * dv.x; wv1.y = DEC * wv1.y - u1 * dv.y;
        wv1.z = DEC * wv1.z - u1 * dv.z; wv1.w = DEC * wv1.w - u1 * dv.w;
        wv2.x = DEC * wv2.x - u2 * dv.x; wv2.y = DEC * wv2.y - u2 * dv.y;
        wv2.z = DEC * wv2.z - u2 * dv.z; wv2.w = DEC * wv2.w - u2 * dv.w;
        *(float4*)(W1 + (size_t)(kb + 0) * 2048 + c0) = wv0;
        *(float4*)(W1 + (size_t)(kb + 1) * 2048 + c0) = wv1;
        *(float4*)(W1 + (size_t)(kb + 2) * 2048 + c0) = wv2;
        if (b == 0) {
            int c = tid * 4;
            float4 dq = *(const float4*)(wsf + OFF_D1Q + c);
            float4 bv = *(float4*)(b1 + c);
            bv.x = DEC * bv.x - LRC * dq.x; bv.y = DEC * bv.y - LRC * dq.y;
            bv.z = DEC * bv.z - LRC * dq.z; bv.w = DEC * bv.w - LRC * dq.w;
            *(float4*)(b1 + c) = bv;
        }
    }

    float4 acc = make_float4(0.f, 0.f, 0.f, 0.f);
    fma4(acc, a0, wv0); fma4(acc, a1, wv1); fma4(acc, a2, wv2);

    float4* red4 = (float4*)smem;
    red4[w * 64 + lane] = acc;
    __syncthreads();
    if (w == 0) {
        float4 s = red4[lane];
#pragma unroll
        for (int q = 1; q < 8; ++q) {
            float4 r2 = red4[q * 64 + lane];
            s.x += r2.x; s.y += r2.y; s.z += r2.z; s.w += r2.w;
        }
        *(float4*)(wsf + OFF_Z1P + (size_t)p * 2048 + c0) = s;
    }
}

// ---------- phases B/C/D-main: fused [W_l/b_l update] + base+decayed matvec ----------
__device__ __forceinline__ void ph_fwd2(int b,
                                        const float* __restrict__ zinP,
                                        const float* __restrict__ zinQ,
                                        const float* __restrict__ bin,
                                        float* __restrict__ W, int Nout,
                                        float* __restrict__ zoutP,
                                        float* __restrict__ zoutQ,
                                        const float* __restrict__ uprev,
                                        const float* __restrict__ vprev,
                                        float* __restrict__ bl,
                                        const float* __restrict__ wsf,
                                        float* smem) {
    int g = b >> 5, p = b & 31;
    int tid = threadIdx.x, w = tid >> 6, lane = tid & 63;
    bool upd = (wsf[OFF_CONDF] != 0.f);

    float* hs = smem; float* hq = smem + 64; float* us = smem + 128;
    if (tid < 64) {
        int k = p * 64 + tid;
        float s = 0.f;
#pragma unroll 8
        for (int pp = 0; pp < 32; ++pp) s += zinP[pp * 2048 + k];
        float bv = bin[k];
        float h = fmaxf(s + bv, 0.f);
        float hqq;
        if (zinQ) {
            float sq = 0.f;
#pragma unroll 8
            for (int pp = 0; pp < 32; ++pp) sq += zinQ[pp * 2048 + k];
            hqq = fmaxf(DEC * (sq + bv), 0.f);
        } else {
            hqq = DEC * h;
        }
        hs[tid] = h; hq[tid] = hqq;
        us[tid] = upd ? (LRC * uprev[k]) : 0.f;
    }
    __syncthreads();
    int c0 = g * 256 + lane * 4;
    float4 vpv = make_float4(0.f, 0.f, 0.f, 0.f);
    if (upd) vpv = *(const float4*)(vprev + c0);
    float4 ap = make_float4(0.f, 0.f, 0.f, 0.f);
    float4 aq = make_float4(0.f, 0.f, 0.f, 0.f);
    if (upd) {
#pragma unroll
        for (int r = 0; r < 8; ++r) {
            int kk = w * 8 + r;
            float* wp = W + (size_t)(p * 64 + kk) * Nout + c0;
            float4 wv = *(const float4*)wp;
            float u = us[kk];
            wv.x = DEC * wv.x - u * vpv.x; wv.y = DEC * wv.y - u * vpv.y;
            wv.z = DEC * wv.z - u * vpv.z; wv.w = DEC * wv.w - u * vpv.w;
            *(float4*)wp = wv;
            float a = hs[kk], a2 = hq[kk];
            fma4(ap, a, wv);
            fma4(aq, a2, wv);
        }
    } else {
#pragma unroll
        for (int r = 0; r < 8; ++r) {
            int kk = w * 8 + r;
            const float4 wv = *(const float4*)(W + (size_t)(p * 64 + kk) * Nout + c0);
            float a = hs[kk], a2 = hq[kk];
            fma4(ap, a, wv);
            fma4(aq, a2, wv);
        }
    }
    if (upd && b == 0) {
        int c = tid * 4;
        if (c < Nout) {
            float4 dq = *(const float4*)(vprev + c);
            float4 bv = *(float4*)(bl + c);
            bv.x = DEC * bv.x - LRC * dq.x; bv.y = DEC * bv.y - LRC * dq.y;
            bv.z = DEC * bv.z - LRC * dq.z; bv.w = DEC * bv.w - LRC * dq.w;
            *(float4*)(bl + c) = bv;
        }
    }
    float4* redP = (float4*)(smem + 256);
    float4* redQ = (float4*)(smem + 2304);
    redP[w * 64 + lane] = ap; redQ[w * 64 + lane] = aq;
    __syncthreads();
    if (w == 0) {
        float4 sp = redP[lane], sq4 = redQ[lane];
#pragma unroll
        for (int q = 1; q < 8; ++q) {
            float4 r2 = redP[q * 64 + lane]; sp.x += r2.x; sp.y += r2.y; sp.z += r2.z; sp.w += r2.w;
            float4 r3 = redQ[q * 64 + lane]; sq4.x += r3.x; sq4.y += r3.y; sq4.z += r3.z; sq4.w += r3.w;
        }
        *(float4*)(zoutP + (size_t)p * Nout + c0) = sp;
        *(float4*)(zoutQ + (size_t)p * Nout + c0) = sq4;
    }
}

// ---------- phase D side-work (runs on blocks idle during the L4 matvec) ----------
__device__ __forceinline__ void ph_finH1(int bb, const float* __restrict__ b1v,
                                         float* __restrict__ wsf) {
    int tid = threadIdx.x;
    if (tid < 128) {
        int e = bb * 128 + tid;
        float s = 0.f;
#pragma unroll 8
        for (int pp = 0; pp < 32; ++pp) s += wsf[OFF_Z1P + pp * 2048 + e];
        float h = fmaxf(s + b1v[e], 0.f);
        wsf[OFF_H1F + e] = h;
        wsf[OFF_H1Q + e] = DEC * h;
    }
}

__device__ __forceinline__ void ph_finH2(int bb, const float* __restrict__ b2v,
                                         float* __restrict__ wsf) {
    int tid = threadIdx.x;
    if (tid < 128) {
        int e = bb * 128 + tid;
        float s = 0.f, sq = 0.f;
#pragma unroll 8
        for (int pp = 0; pp < 32; ++pp) {
            s += wsf[OFF_Z2P + pp * 2048 + e];
            sq += wsf[OFF_Z2Q + pp * 2048 + e];
        }
        float bv = b2v[e];
        wsf[OFF_H2F + e] = fmaxf(s + bv, 0.f);
        wsf[OFF_H2Q + e] = fmaxf(DEC * (sq + bv), 0.f);
    }
}

__device__ __forceinline__ void ph_normX(const float* __restrict__ xt,
                                         float* __restrict__ wsf, float* smem) {
    int tid = threadIdx.x;
    float v = 0.f;
    for (int e = tid; e < 768; e += 512) { float xv = xt[e]; v += xv * xv; }
    float s = block_reduce_512s(v, smem);
    if (tid == 0) wsf[OFF_NSQ + 0] = s;
}

__device__ __forceinline__ void ph_normH(const float* __restrict__ zin,
                                         const float* __restrict__ bias, int idx,
                                         float* __restrict__ wsf, float* smem) {
    int tid = threadIdx.x;
    float v = 0.f;
    for (int e = tid; e < 2048; e += 512) {
        float s = 0.f;
#pragma unroll 8
        for (int pp = 0; pp < 32; ++pp) s += zin[pp * 2048 + e];
        float h = fmaxf(s + bias[e], 0.f);
        v += h * h;
    }
    float s2 = block_reduce_512s(v, smem);
    if (tid == 0) wsf[OFF_NSQ + idx] = s2;
}

// ---------- phase E: d4 finalize + h3 finalize + W4^T backward + ||d4||^2 ----------
__device__ __forceinline__ void ph_bwd4(const float* __restrict__ W4,
                                        const float* __restrict__ b3v,
                                        const float* __restrict__ b4v,
                                        const float* __restrict__ xt,
                                        float* __restrict__ wsf, float* smem) {
    float* dsP = smem;              // 768 used
    float* dsQ = smem + 2048;       // 768 used
    float* red = smem + 4096;       // 512
    float* sqw = smem + 4608;       // 8
    float* h3f = smem + 4616;       // 8
    float* h3q = smem + 4624;       // 8
    int tid = threadIdx.x, b = blockIdx.x;

    // h3 for this block's 8 rows (same pp-ordered arithmetic as old k_fin)
    if (tid < 8) {
        int j = b * 8 + tid;
        float s = 0.f, sq = 0.f;
#pragma unroll 8
        for (int pp = 0; pp < 32; ++pp) {
            s += wsf[OFF_Z3P + pp * 2048 + j];
            sq += wsf[OFF_Z3Q + pp * 2048 + j];
        }
        float bv = b3v[j];
        float hf = fmaxf(s + bv, 0.f);
        float hqv = fmaxf(DEC * (sq + bv), 0.f);
        wsf[OFF_H3F + j] = hf; wsf[OFF_H3Q + j] = hqv;
        h3f[tid] = hf; h3q[tid] = hqv;
    }
    // d4 build (redundant per block; identical pp-ordered arithmetic)
    for (int e = tid; e < 768; e += 512) {
        float s = 0.f, sq = 0.f;
#pragma unroll 8
        for (int pp = 0; pp < 32; ++pp) {
            s += wsf[OFF_Z4P + pp * 768 + e];
            sq += wsf[OFF_Z4Q + pp * 768 + e];
        }
        float bv = b4v[e], tv = xt[e];
        dsP[e] = 2.f * ((s + bv) - tv) * (1.f / 768.f);
        dsQ[e] = 2.f * (DEC * (sq + bv) - tv) * (1.f / 768.f);
    }
    __syncthreads();
    if (b == 0) {
        for (int e = tid; e < 768; e += 512) {
            wsf[OFF_D4F + e] = dsP[e];
            wsf[OFF_D4Q + e] = dsQ[e];
        }
        float v = 0.f;
        for (int e = tid; e < 768; e += 512) { float d = dsP[e]; v += d * d; }
        float s = block_reduce_512s(v, red);
        if (tid == 0) wsf[OFF_NSQ + 4] = s;
    }
    int w = tid >> 6, lane = tid & 63;
    const float* row = W4 + (size_t)(b * 8 + w) * 768;
    float apv = 0.f, aqv = 0.f;
    for (int k4 = lane * 4; k4 < 768; k4 += 256) {
        const float4 wv = *(const float4*)(row + k4);
        apv += wv.x * dsP[k4] + wv.y * dsP[k4 + 1] + wv.z * dsP[k4 + 2] + wv.w * dsP[k4 + 3];
        aqv += wv.x * dsQ[k4] + wv.y * dsQ[k4 + 1] + wv.z * dsQ[k4 + 2] + wv.w * dsQ[k4 + 3];
    }
#pragma unroll
    for (int off = 32; off > 0; off >>= 1) {
        apv += __shfl_down(apv, off);
        aqv += __shfl_down(aqv, off);
    }
    if (lane == 0) {
        float dp = (h3f[w] > 0.f) ? apv : 0.f;
        float dq = (h3q[w] > 0.f) ? DEC * aqv : 0.f;
        wsf[OFF_D3F + b * 8 + w] = dp;
        wsf[OFF_D3Q + b * 8 + w] = dq;
        sqw[w] = dp * dp;
    }
    __syncthreads();
    if (tid == 0) {
        float s = 0.f;
#pragma unroll
        for (int q = 0; q < 8; ++q) s += sqw[q];
        wsf[OFF_SL3 + b] = s;
    }
}

// ---------- phases F/G: fused W^T backward, wave-per-row ----------
__device__ __forceinline__ void ph_bwd(int b, const float* __restrict__ W, int K,
                                       const float* __restrict__ dinP,
                                       const float* __restrict__ dinQ,
                                       const float* __restrict__ hP,
                                       const float* __restrict__ hQ,
                                       float* __restrict__ doutP,
                                       float* __restrict__ doutQ,
                                       float* __restrict__ slot,
                                       float* smem) {
    float* dsP = smem;
    float* dsQ = smem + 2048;
    float* sqw = smem + 4096;
    int tid = threadIdx.x;
    for (int k = tid; k < K; k += 512) { dsP[k] = dinP[k]; dsQ[k] = dinQ[k]; }
    __syncthreads();
    int w = tid >> 6, lane = tid & 63;
    int j = b * 8 + w;
    const float* row = W + (size_t)j * K;
    float ap = 0.f, aq = 0.f;
    for (int k4 = lane * 4; k4 < K; k4 += 256) {
        const float4 wv = *(const float4*)(row + k4);
        ap += wv.x * dsP[k4] + wv.y * dsP[k4 + 1] + wv.z * dsP[k4 + 2] + wv.w * dsP[k4 + 3];
        aq += wv.x * dsQ[k4] + wv.y * dsQ[k4 + 1] + wv.z * dsQ[k4 + 2] + wv.w * dsQ[k4 + 3];
    }
#pragma unroll
    for (int off = 32; off > 0; off >>= 1) {
        ap += __shfl_down(ap, off);
        aq += __shfl_down(aq, off);
    }
    if (lane == 0) {
        float dp = (hP[j] > 0.f) ? ap : 0.f;
        float dq = (hQ[j] > 0.f) ? DEC * aq : 0.f;
        doutP[j] = dp;
        doutQ[j] = dq;
        sqw[w] = dp * dp;
    }
    __syncthreads();
    if (tid == 0) {
        float s = 0.f;
#pragma unroll
        for (int q = 0; q < 8; ++q) s += sqw[q];
        slot[b] = s;
    }
}

// ---------- epilogue: apply the LAST step's update ----------
__device__ __forceinline__ void ph_upd(int step, float* __restrict__ wsf,
                                       float* __restrict__ W1, float* __restrict__ b1,
                                       float* __restrict__ W2, float* __restrict__ b2,
                                       float* __restrict__ W3, float* __restrict__ b3,
                                       float* __restrict__ W4, float* __restrict__ b4,
                                       const float* __restrict__ xt, float* smem) {
    int tid = threadIdx.x, b = blockIdx.x;
    float* red = smem;
    float s3 = block_reduce_512s((tid < 256) ? wsf[OFF_SL3 + tid] : 0.f, red);
    float s2 = block_reduce_512s((tid < 256) ? wsf[OFF_SL2 + tid] : 0.f, red);
    float s1 = block_reduce_512s((tid < 256) ? wsf[OFF_SL1 + tid] : 0.f, red);
    float* condp = smem + 512;
    if (tid == 0) {
        float nx = sqrtf(wsf[OFF_NSQ + 0]);
        float nh1 = sqrtf(wsf[OFF_NSQ + 1]);
        float nh2 = sqrtf(wsf[OFF_NSQ + 2]);
        float nh3 = sqrtf(wsf[OFF_NSQ + 3]);
        float nd4 = sqrtf(wsf[OFF_NSQ + 4]);
        float nd3 = sqrtf(s3), nd2 = sqrtf(s2), nd1 = sqrtf(s1);
        float surprise = nx * nd1 + nd1 + nh1 * nd2 + nd2 + nh2 * nd3 + nd3 + nh3 * nd4 + nd4;
        float bufold = wsf[OFF_BUF + (step & 1)];
        float bufnew = (step == 0) ? surprise : (0.9f * bufold + 0.1f * surprise);
        wsf[OFF_BUF + ((step + 1) & 1)] = bufnew;
        condp[0] = (bufnew > 0.1f) ? 1.f : 0.f;
    }
    __syncthreads();
    if (condp[0] == 0.f) return;

    const float* d1q = wsf + OFF_D1Q;
    const float* d2q = wsf + OFF_D2Q;
    const float* d3q = wsf + OFF_D3Q;
    const float* d4q = wsf + OFF_D4Q;
    const float* h1q = wsf + OFF_H1Q;
    const float* h2q = wsf + OFF_H2Q;
    const float* h3q = wsf + OFF_H3Q;
    int c = tid * 4;
    {
        float4 dv = *(const float4*)(d1q + c);
#pragma unroll
        for (int r = 0; r < 3; ++r) {
            int i = b * 3 + r;
            float u = LRC * xt[i];
            float4* wp = (float4*)(W1 + (size_t)i * 2048 + c);
            float4 wv = *wp;
            wv.x = DEC * wv.x - u * dv.x; wv.y = DEC * wv.y - u * dv.y;
            wv.z = DEC * wv.z - u * dv.z; wv.w = DEC * wv.w - u * dv.w;
            *wp = wv;
        }
    }
    {
        float4 dv = *(const float4*)(d2q + c);
#pragma unroll
        for (int r = 0; r < 8; ++r) {
            int i = b * 8 + r;
            float u = LRC * h1q[i];
            float4* wp = (float4*)(W2 + (size_t)i * 2048 + c);
            float4 wv = *wp;
            wv.x = DEC * wv.x - u * dv.x; wv.y = DEC * wv.y - u * dv.y;
            wv.z = DEC * wv.z - u * dv.z; wv.w = DEC * wv.w - u * dv.w;
            *wp = wv;
        }
    }
    {
        float4 dv = *(const float4*)(d3q + c);
#pragma unroll
        for (int r = 0; r < 8; ++r) {
            int i = b * 8 + r;
            float u = LRC * h2q[i];
            float4* wp = (float4*)(W3 + (size_t)i * 2048 + c);
            float4 wv = *wp;
            wv.x = DEC * wv.x - u * dv.x; wv.y = DEC * wv.y - u * dv.y;
            wv.z = DEC * wv.z - u * dv.z; wv.w = DEC * wv.w - u * dv.w;
            *wp = wv;
        }
    }
    if (tid < 192) {
        float4 dv = *(const float4*)(d4q + c);
#pragma unroll
        for (int r = 0; r < 8; ++r) {
            int i = b * 8 + r;
            float u = LRC * h3q[i];
            float4* wp = (float4*)(W4 + (size_t)i * 768 + c);
            float4 wv = *wp;
            wv.x = DEC * wv.x - u * dv.x; wv.y = DEC * wv.y - u * dv.y;
            wv.z = DEC * wv.z - u * dv.z; wv.w = DEC * wv.w - u * dv.w;
            *wp = wv;
        }
    }
    if (b == 0) {
        float4 dv = *(const float4*)(d1q + c);
        float4* bp = (float4*)(b1 + c);
        float4 bv = *bp;
        bv.x = DEC * bv.x - LRC * dv.x; bv.y = DEC * bv.y - LRC * dv.y;
        bv.z = DEC * bv.z - LRC * dv.z; bv.w = DEC * bv.w - LRC * dv.w;
        *bp = bv;
    } else if (b == 1) {
        float4 dv = *(const float4*)(d2q + c);
        float4* bp = (float4*)(b2 + c);
        float4 bv = *bp;
        bv.x = DEC * bv.x - LRC * dv.x; bv.y = DEC * bv.y - LRC * dv.y;
        bv.z = DEC * bv.z - LRC * dv.z; bv.w = DEC * bv.w - LRC * dv.w;
        *bp = bv;
    } else if (b == 2) {
        float4 dv = *(const float4*)(d3q + c);
        float4* bp = (float4*)(b3 + c);
        float4 bv = *bp;
        bv.x = DEC * bv.x - LRC * dv.x; bv.y = DEC * bv.y - LRC * dv.y;
        bv.z = DEC * bv.z - LRC * dv.z; bv.w = DEC * bv.w - LRC * dv.w;
        *bp = bv;
    } else if (b == 3 && tid < 192) {
        float4 dv = *(const float4*)(d4q + c);
        float4* bp = (float4*)(b4 + c);
        float4 bv = *bp;
        bv.x = DEC * bv.x - LRC * dv.x; bv.y = DEC * bv.y - LRC * dv.y;
        bv.z = DEC * bv.z - LRC * dv.z; bv.w = DEC * bv.w - LRC * dv.w;
        *bp = bv;
    }
}

// ---------- barrier-state init ----------
__global__ __launch_bounds__(1024) void k_zero(unsigned* __restrict__ bar) {
    bar[threadIdx.x] = 0u;
}

// ---------- the entire TTT scan as one persistent kernel ----------
__global__ __launch_bounds__(512) void k_scan(const float* __restrict__ x,
                                              float* __restrict__ W1, float* __restrict__ b1,
                                              float* __restrict__ W2, float* __restrict__ b2,
                                              float* __restrict__ W3, float* __restrict__ b3,
                                              float* __restrict__ W4, float* __restrict__ b4,
                                              float* __restrict__ wsf,
                                              const int* __restrict__ flag) {
    if (*flag == 0) return;          // uniform across grid; no barrier touched
    __shared__ float smem[4640];
    unsigned* bar = (unsigned*)(wsf + OFF_HA);
    int b = blockIdx.x;
    for (int s = 0; s < 1024; ++s) {
        const float* xt = x + (size_t)s * 3072;
        const float* xprev = x + (size_t)(s > 0 ? s - 1 : 0) * 3072;
        // A: fused W1/b1 update (step s-1) + cond + z1 partials
        ph_fwd1(s, xt, xprev, W1, b1, wsf, smem);
        gbar(bar);
        // B: layer 2
        ph_fwd2(b, wsf + OFF_Z1P, nullptr, b1, W2, 2048, wsf + OFF_Z2P, wsf + OFF_Z2Q,
                wsf + OFF_H1Q, wsf + OFF_D2Q, b2, wsf, smem);
        gbar(bar);
        // C: layer 3
        ph_fwd2(b, wsf + OFF_Z2P, wsf + OFF_Z2Q, b2, W3, 2048, wsf + OFF_Z3P, wsf + OFF_Z3Q,
                wsf + OFF_H2Q, wsf + OFF_D3Q, b3, wsf, smem);
        gbar(bar);
        // D: layer 4 on blocks 0..95; h1/h2 finalize + norms on otherwise-idle blocks
        if (b < 96) {
            ph_fwd2(b, wsf + OFF_Z3P, wsf + OFF_Z3Q, b3, W4, 768, wsf + OFF_Z4P, wsf + OFF_Z4Q,
                    wsf + OFF_H3Q, wsf + OFF_D4Q, b4, wsf, smem);
        } else if (b < 112) {
            ph_finH1(b - 96, b1, wsf);
        } else if (b < 128) {
            ph_finH2(b - 112, b2, wsf);
        } else if (b == 144) {
            ph_normX(xt, wsf, smem);
        } else if (b == 145) {
            ph_normH(wsf + OFF_Z1P, b1, 1, wsf, smem);
        } else if (b == 146) {
            ph_normH(wsf + OFF_Z2P, b2, 2, wsf, smem);
        } else if (b == 147) {
            ph_normH(wsf + OFF_Z3P, b3, 3, wsf, smem);
        }
        gbar(bar);
        // E: d4+h3 finalize + W4^T backward + ||d4||^2
        ph_bwd4(W4, b3, b4, xt, wsf, smem);
        gbar(bar);
        // F: W3^T backward
        ph_bwd(b, W3, 2048, wsf + OFF_D3F, wsf + OFF_D3Q, wsf + OFF_H2F, wsf + OFF_H2Q,
               wsf + OFF_D2F, wsf + OFF_D2Q, wsf + OFF_SL2, smem);
        gbar(bar);
        // G: W2^T backward
        ph_bwd(b, W2, 2048, wsf + OFF_D2F, wsf + OFF_D2Q, wsf + OFF_H1F, wsf + OFF_H1Q,
               wsf + OFF_D1F, wsf + OFF_D1Q, wsf + OFF_SL1, smem);
        gbar(bar);
    }
    // apply the final (step 1023) update
    ph_upd(1023, wsf, W1, b1, W2, b2, W3, b3, W4, b4, x + (size_t)1023 * 3072, smem);
}

// ---------- final batch forward: fp32 tiled GEMM C = act(A@W + bias) ----------
__global__ __launch_bounds__(256) void k_gemm(const float* __restrict__ A,
                                              const float* __restrict__ W,
                                              const float* __restrict__ bias,
                                              float* __restrict__ C,
                                              int M, int N, int K, int do_relu) {
    __shared__ float sA[16][64];
    __shared__ float sB[16][128];
    int bn = blockIdx.x, bm = blockIdx.y;
    int m0 = bm * 64, n0 = bn * 128;
    int tid = threadIdx.x;
    int tx = tid & 31, ty = tid >> 5;
    float acc[8][4];
#pragma unroll
    for (int i = 0; i < 8; ++i)
#pragma unroll
        for (int j = 0; j < 4; ++j) acc[i][j] = 0.f;

    for (int kt = 0; kt < K; kt += 16) {
        {
            int r = tid >> 2, cc = (tid & 3) * 4;
            const float4 a4 = *(const float4*)(A + (size_t)(m0 + r) * K + kt + cc);
            sA[cc + 0][r] = a4.x; sA[cc + 1][r] = a4.y; sA[cc + 2][r] = a4.z; sA[cc + 3][r] = a4.w;
        }
        {
            int r = tid >> 5, cc = (tid & 31) * 4;
            *(float4*)(&sB[r][cc]) = *(const float4*)(W + (size_t)(kt + r) * N + n0 + cc);
            *(float4*)(&sB[r + 8][cc]) = *(const float4*)(W + (size_t)(kt + r + 8) * N + n0 + cc);
        }
        __syncthreads();
#pragma unroll
        for (int k = 0; k < 16; ++k) {
            float av[8];
#pragma unroll
            for (int i = 0; i < 8; ++i) av[i] = sA[k][ty * 8 + i];
            float bx = sB[k][tx * 4 + 0], by = sB[k][tx * 4 + 1];
            float bz = sB[k][tx * 4 + 2], bw = sB[k][tx * 4 + 3];
#pragma unroll
            for (int i = 0; i < 8; ++i) {
                acc[i][0] += av[i] * bx; acc[i][1] += av[i] * by;
                acc[i][2] += av[i] * bz; acc[i][3] += av[i] * bw;
            }
        }
        __syncthreads();
    }
    float bx = bias[n0 + tx * 4 + 0], by = bias[n0 + tx * 4 + 1];
    float bz = bias[n0 + tx * 4 + 2], bw = bias[n0 + tx * 4 + 3];
#pragma unroll
    for (int i = 0; i < 8; ++i) {
        int m = m0 + ty * 8 + i;
        float4 v;
        v.x = acc[i][0] + bx; v.y = acc[i][1] + by;
        v.z = acc[i][2] + bz; v.w = acc[i][3] + bw;
        if (do_relu) {
            v.x = fmaxf(v.x, 0.f); v.y = fmaxf(v.y, 0.f);
            v.z = fmaxf(v.z, 0.f); v.w = fmaxf(v.w, 0.f);
        }
        *(float4*)(C + (size_t)m * N + n0 + tx * 4) = v;
    }
}

__global__ __launch_bounds__(128) void k_colsum(const float* __restrict__ Y,
                                                float* __restrict__ out) {
    int c = blockIdx.x * 128 + threadIdx.x;
    int r0 = blockIdx.y * 128;
    float s = 0.f;
    for (int r = 0; r < 128; ++r) s += Y[(size_t)(r0 + r) * 768 + c];
    out[blockIdx.y * 768 + c] = s;
}

__global__ __launch_bounds__(768) void k_out(const float* __restrict__ msum,
                                             float* __restrict__ out) {
    int c = threadIdx.x;
    float s = 0.f;
#pragma unroll
    for (int i = 0; i < 32; ++i) s += msum[i * 768 + c];
    out[c] = s * (1.f / 4096.f);
}

extern "C" void kernel_launch(void* const* d_in, const int* in_sizes, int n_in,
                              void* d_out, int out_size, void* d_ws, size_t ws_size,
                              hipStream_t stream) {
    const float* x = (const float*)d_in[0];
    float* W1 = (float*)d_in[1];
    float* b1 = (float*)d_in[2];
    float* W2 = (float*)d_in[3];
    float* b2 = (float*)d_in[4];
    float* W3 = (float*)d_in[5];
    float* b3 = (float*)d_in[6];
    float* W4 = (float*)d_in[7];
    float* b4 = (float*)d_in[8];
    const int* flag = (const int*)d_in[9];
    float* wsf = (float*)d_ws;

    // barrier state lives in the HA region (unused until the final forward)
    unsigned* bar = (unsigned*)(wsf + OFF_HA);
    k_zero<<<1, 1024, 0, stream>>>(bar);

    // ---- entire 1024-step TTT scan: ONE persistent kernel, 7 grid barriers/step ----
    k_scan<<<256, 512, 0, stream>>>(x, W1, b1, W2, b2, W3, b3, W4, b4, wsf, flag);

    // ---- final forward over all 4096 tokens, chunked by 1024, + mean ----
    float* HA = wsf + OFF_HA;
    float* HB = wsf + OFF_HB;
    for (int ch = 0; ch < 4; ++ch) {
        const float* Xc = x + (size_t)ch * 1024 * 768;
        k_gemm<<<dim3(16, 16), 256, 0, stream>>>(Xc, W1, b1, HA, 1024, 2048, 768, 1);
        k_gemm<<<dim3(16, 16), 256, 0, stream>>>(HA, W2, b2, HB, 1024, 2048, 2048, 1);
        k_gemm<<<dim3(16, 16), 256, 0, stream>>>(HB, W3, b3, HA, 1024, 2048, 2048, 1);
        k_gemm<<<dim3(6, 16), 256, 0, stream>>>(HA, W4, b4, HB, 1024, 768, 2048, 0);
        k_colsum<<<dim3(6, 8), 128, 0, stream>>>(HB, wsf + OFF_MSUM + (size_t)ch * 8 * 768);
    }
    k_out<<<1, 768, 0, stream>>>(wsf + OFF_MSUM, (float*)d_out);
}

// Round 2
// 98167.725 us; speedup vs baseline: 2.1561x; 2.1561x over previous
//
#include <hip/hip_runtime.h>
#include <cstddef>

#define LRC 0.001f
#define DEC 0.99f

typedef float f32x4 __attribute__((ext_vector_type(4)));

// ---------------- workspace layout (float offsets) ----------------
static const size_t OFF_Z1P = 0;            // [32][2048]
static const size_t OFF_Z2P = 65536;        // [32][2048]
static const size_t OFF_Z2Q = 131072;
static const size_t OFF_Z3P = 196608;
static const size_t OFF_Z3Q = 262144;
static const size_t OFF_Z4P = 327680;       // [32][768]
static const size_t OFF_Z4Q = 352256;
static const size_t OFF_H1F = 376832;       // 2048 each below
static const size_t OFF_H1Q = 378880;
static const size_t OFF_H2F = 380928;
static const size_t OFF_H2Q = 382976;
static const size_t OFF_H3F = 385024;
static const size_t OFF_H3Q = 387072;
static const size_t OFF_D4F = 389120;       // 768
static const size_t OFF_D4Q = 389888;       // 768
static const size_t OFF_D3F = 390656;       // 2048
static const size_t OFF_D3Q = 392704;
static const size_t OFF_D2F = 394752;
static const size_t OFF_D2Q = 396800;
static const size_t OFF_D1F = 398848;
static const size_t OFF_D1Q = 400896;
static const size_t OFF_NSQ = 402944;       // 16: 0=x,1=h1,2=h2,3=h3,4=d4
static const size_t OFF_SL3 = 402960;       // 256 per-block |d3|^2 partials
static const size_t OFF_SL2 = 403216;
static const size_t OFF_SL1 = 403472;
static const size_t OFF_BUF = 403728;       // 2 (ping-pong EMA buffer)
static const size_t OFF_CONDF = 403730;     // 1
static const size_t OFF_MSUM = 403732;      // [32][768]
static const size_t OFF_HA  = 428308;       // 1024*2048 (first KBs double as barrier state during scan)
static const size_t OFF_HB  = 2525460;      // 1024*2048

// ---------------- coherent (L2-bypass, L3-resident) access helpers ----------------
__device__ __forceinline__ float clf(const float* p) {
    return __hip_atomic_load(p, __ATOMIC_RELAXED, __HIP_MEMORY_SCOPE_AGENT);
}
__device__ __forceinline__ void csf(float* p, float v) {
    __hip_atomic_store(p, v, __ATOMIC_RELAXED, __HIP_MEMORY_SCOPE_AGENT);
}
// wide coherent load: value NOT ready until vwait() — batch loads, then vwait, then use
__device__ __forceinline__ f32x4 cl4(const float* p) {
    f32x4 r;
    asm volatile("global_load_dwordx4 %0, %1, off sc0 sc1" : "=&v"(r) : "v"(p) : "memory");
    return r;
}
__device__ __forceinline__ void cs4(float* p, f32x4 v) {
    asm volatile("global_store_dwordx4 %0, %1, off sc0 sc1" :: "v"(p), "v"(v) : "memory");
}
__device__ __forceinline__ void vwait() {
    asm volatile("s_waitcnt vmcnt(0)" ::: "memory");
    __builtin_amdgcn_sched_barrier(0);   // rule #18: pin uses after the waitcnt
}
__device__ __forceinline__ f32x4 tov(float4 v) { f32x4 r; r.x=v.x; r.y=v.y; r.z=v.z; r.w=v.w; return r; }
__device__ __forceinline__ void fma4v(float4& a, float s, const f32x4& w) {
    a.x += s * w.x; a.y += s * w.y; a.z += s * w.z; a.w += s * w.w;
}
__device__ __forceinline__ void rmw4(f32x4& t, float u, const f32x4& dv) {
    t.x = DEC * t.x - u * dv.x; t.y = DEC * t.y - u * dv.y;
    t.z = DEC * t.z - u * dv.z; t.w = DEC * t.w - u * dv.w;
}

__device__ __forceinline__ float block_reduce_512s(float v, float* red) {
    int t = threadIdx.x;
    red[t] = v;
    __syncthreads();
    for (int st = 256; st > 0; st >>= 1) {
        if (t < st) red[t] += red[t + st];
        __syncthreads();
    }
    float r = red[0];
    __syncthreads();
    return r;
}

// ---- grid barrier: NO cache-maintenance (all cross-block data goes through sc0sc1) ----
// layout (unsigned idx at bar): gen@0, root@32, grp[i]@64+32*i (i<16)
__device__ __forceinline__ void gbar(unsigned* bar) {
    asm volatile("s_waitcnt vmcnt(0) lgkmcnt(0)" ::: "memory");  // per-wave: drain sc1 stores
    __syncthreads();
    if (threadIdx.x == 0) {
        unsigned g = __hip_atomic_load(bar, __ATOMIC_RELAXED, __HIP_MEMORY_SCOPE_AGENT);
        unsigned* grp = bar + 64 + ((blockIdx.x >> 4) << 5);
        bool released = false;
        if (__hip_atomic_fetch_add(grp, 1u, __ATOMIC_RELAXED, __HIP_MEMORY_SCOPE_AGENT) == 15u) {
            if (__hip_atomic_fetch_add(bar + 32, 1u, __ATOMIC_RELAXED, __HIP_MEMORY_SCOPE_AGENT) == 15u) {
#pragma unroll
                for (int i = 0; i < 16; ++i)
                    __hip_atomic_store(bar + 64 + (i << 5), 0u, __ATOMIC_RELAXED, __HIP_MEMORY_SCOPE_AGENT);
                __hip_atomic_store(bar + 32, 0u, __ATOMIC_RELAXED, __HIP_MEMORY_SCOPE_AGENT);
                __hip_atomic_store(bar, g + 1u, __ATOMIC_RELEASE, __HIP_MEMORY_SCOPE_AGENT);
                released = true;
            }
        }
        if (!released) {
            while (__hip_atomic_load(bar, __ATOMIC_RELAXED, __HIP_MEMORY_SCOPE_AGENT) == g)
                __builtin_amdgcn_s_sleep(2);
            (void)__hip_atomic_load(bar, __ATOMIC_ACQUIRE, __HIP_MEMORY_SCOPE_AGENT);
        }
    }
    __syncthreads();
}

// ---------- phase A: fused [apply step-(s-1) W1/b1 update] + cond + z1 partials ----------
__device__ __forceinline__ void ph_fwd1(int step, const float* __restrict__ xt,
                                        const float* __restrict__ xprev,
                                        float* __restrict__ W1, float* __restrict__ b1,
                                        float* __restrict__ wsf, float* smem) {
    int b = blockIdx.x, g = b >> 5, p = b & 31;
    int tid = threadIdx.x, w = tid >> 6, lane = tid & 63;
    int c0 = g * 256 + lane * 4;
    int kb = p * 24 + w * 3;

    f32x4 wv0 = cl4(W1 + (size_t)(kb + 0) * 2048 + c0);
    f32x4 wv1 = cl4(W1 + (size_t)(kb + 1) * 2048 + c0);
    f32x4 wv2 = cl4(W1 + (size_t)(kb + 2) * 2048 + c0);
    f32x4 dv  = cl4(wsf + OFF_D1Q + c0);          // garbage at step 0 (unused: cond=0)
    float a0 = xt[kb + 0], a1 = xt[kb + 1], a2 = xt[kb + 2];
    float u0 = 0.f, u1 = 0.f, u2 = 0.f;
    if (step > 0) { u0 = LRC * xprev[kb + 0]; u1 = LRC * xprev[kb + 1]; u2 = LRC * xprev[kb + 2]; }

    float* cnd = smem + 2048;
    float cond = 0.f;
    if (step > 0) {
        if (w < 3) {
            const float* sl = wsf + (w == 0 ? OFF_SL1 : (w == 1 ? OFF_SL2 : OFF_SL3));
            float v = clf(sl + lane) + clf(sl + lane + 64) + clf(sl + lane + 128) + clf(sl + lane + 192);
#pragma unroll
            for (int off = 32; off > 0; off >>= 1) v += __shfl_down(v, off);
            if (lane == 0) cnd[w] = v;
        }
        __syncthreads();
        float nd1 = sqrtf(cnd[0]), nd2 = sqrtf(cnd[1]), nd3 = sqrtf(cnd[2]);
        float nx  = sqrtf(clf(wsf + OFF_NSQ + 0));
        float nh1 = sqrtf(clf(wsf + OFF_NSQ + 1));
        float nh2 = sqrtf(clf(wsf + OFF_NSQ + 2));
        float nh3 = sqrtf(clf(wsf + OFF_NSQ + 3));
        float nd4 = sqrtf(clf(wsf + OFF_NSQ + 4));
        float surprise = nx * nd1 + nd1 + nh1 * nd2 + nd2 + nh2 * nd3 + nd3 + nh3 * nd4 + nd4;
        float bufold = clf(wsf + OFF_BUF + ((step - 1) & 1));
        float bufnew = (step == 1) ? surprise : (0.9f * bufold + 0.1f * surprise);
        cond = (bufnew > 0.1f) ? 1.f : 0.f;
        if (b == 0 && tid == 0) {
            csf(wsf + OFF_BUF + (step & 1), bufnew);
            csf(wsf + OFF_CONDF, cond);
        }
    } else {
        if (b == 0 && tid == 0) csf(wsf + OFF_CONDF, 0.f);
    }

    vwait();   // wv0..wv2, dv ready
    if (cond != 0.f) {
        rmw4(wv0, u0, dv); rmw4(wv1, u1, dv); rmw4(wv2, u2, dv);
        cs4(W1 + (size_t)(kb + 0) * 2048 + c0, wv0);
        cs4(W1 + (size_t)(kb + 1) * 2048 + c0, wv1);
        cs4(W1 + (size_t)(kb + 2) * 2048 + c0, wv2);
        if (b == 0) {
            int c = tid * 4;
            f32x4 dq = cl4(wsf + OFF_D1Q + c);
            f32x4 bv = cl4(b1 + c);
            vwait();
            rmw4(bv, LRC, dq);
            cs4(b1 + c, bv);
        }
    }

    float4 acc = make_float4(0.f, 0.f, 0.f, 0.f);
    fma4v(acc, a0, wv0); fma4v(acc, a1, wv1); fma4v(acc, a2, wv2);

    float4* red = (float4*)smem;
    red[w * 64 + lane] = acc;
    __syncthreads();
    if (w == 0) {
        float4 s = red[lane];
#pragma unroll
        for (int q = 1; q < 8; ++q) {
            float4 r2 = red[q * 64 + lane];
            s.x += r2.x; s.y += r2.y; s.z += r2.z; s.w += r2.w;
        }
        cs4(wsf + OFF_Z1P + (size_t)p * 2048 + c0, tov(s));
    }
}

// ---------- phases B/C/D-main: fused [W_l/b_l update] + base+decayed matvec ----------
// smem: bufP@0[2048] bufQ@2048[2048] hs@4096 hq@4160 us@4224 cond@4288 redP@4352 redQ@6400
__device__ __forceinline__ void ph_fwd2(int b, const float* __restrict__ zinP,
                                        const float* __restrict__ zinQ,
                                        const float* __restrict__ bin,
                                        float* __restrict__ W, int Nout,
                                        float* __restrict__ zoutP, float* __restrict__ zoutQ,
                                        const float* __restrict__ uprev,
                                        const float* __restrict__ vprev,
                                        float* __restrict__ bl,
                                        const float* __restrict__ wsf, float* smem) {
    int g = b >> 5, p = b & 31;
    int tid = threadIdx.x, w = tid >> 6, lane = tid & 63;
    if (tid == 0) smem[4288] = clf(wsf + OFF_CONDF);
    {
        int l4 = tid * 4;
        const float* zp = zinP + p * 64 + (l4 >> 6) * 2048 + (l4 & 63);
        f32x4 vP = cl4(zp);
        if (zinQ) {
            const float* zq = zinQ + p * 64 + (l4 >> 6) * 2048 + (l4 & 63);
            f32x4 vQ = cl4(zq);
            vwait();
            *(f32x4*)(smem + l4) = vP;
            *(f32x4*)(smem + 2048 + l4) = vQ;
        } else {
            vwait();
            *(f32x4*)(smem + l4) = vP;
        }
    }
    __syncthreads();
    bool upd = (smem[4288] != 0.f);
    if (tid < 64) {
        int k = p * 64 + tid;
        float s = 0.f;
#pragma unroll 8
        for (int pp = 0; pp < 32; ++pp) s += smem[pp * 64 + tid];
        float bv = clf(bin + k);
        float h = fmaxf(s + bv, 0.f);
        float hqq;
        if (zinQ) {
            float sq = 0.f;
#pragma unroll 8
            for (int pp = 0; pp < 32; ++pp) sq += smem[2048 + pp * 64 + tid];
            hqq = fmaxf(DEC * (sq + bv), 0.f);
        } else {
            hqq = DEC * h;
        }
        smem[4096 + tid] = h; smem[4160 + tid] = hqq;
        smem[4224 + tid] = upd ? (LRC * clf(uprev + k)) : 0.f;
    }
    __syncthreads();
    int c0 = g * 256 + lane * 4;
    float4 ap = make_float4(0.f, 0.f, 0.f, 0.f);
    float4 aq = make_float4(0.f, 0.f, 0.f, 0.f);
    if (upd) {
        f32x4 vp = cl4(vprev + c0);
        f32x4 wv[8];
#pragma unroll
        for (int r = 0; r < 8; ++r)
            wv[r] = cl4(W + (size_t)(p * 64 + w * 8 + r) * Nout + c0);
        vwait();
#pragma unroll
        for (int r = 0; r < 8; ++r) {
            int kk = w * 8 + r;
            float u = smem[4224 + kk];
            f32x4 t = wv[r];
            rmw4(t, u, vp);
            cs4(W + (size_t)(p * 64 + kk) * Nout + c0, t);
            fma4v(ap, smem[4096 + kk], t);
            fma4v(aq, smem[4160 + kk], t);
        }
    } else {
        f32x4 wv[8];
#pragma unroll
        for (int r = 0; r < 8; ++r)
            wv[r] = cl4(W + (size_t)(p * 64 + w * 8 + r) * Nout + c0);
        vwait();
#pragma unroll
        for (int r = 0; r < 8; ++r) {
            int kk = w * 8 + r;
            fma4v(ap, smem[4096 + kk], wv[r]);
            fma4v(aq, smem[4160 + kk], wv[r]);
        }
    }
    if (upd && b == 0) {
        int c = tid * 4;
        if (c < Nout) {
            f32x4 dq = cl4(vprev + c);
            f32x4 bv = cl4(bl + c);
            vwait();
            rmw4(bv, LRC, dq);
            cs4(bl + c, bv);
        }
    }
    float4* redP = (float4*)(smem + 4352);
    float4* redQ = (float4*)(smem + 6400);
    redP[w * 64 + lane] = ap; redQ[w * 64 + lane] = aq;
    __syncthreads();
    if (w == 0) {
        float4 sp = redP[lane], sq4 = redQ[lane];
#pragma unroll
        for (int q = 1; q < 8; ++q) {
            float4 r2 = redP[q * 64 + lane]; sp.x += r2.x; sp.y += r2.y; sp.z += r2.z; sp.w += r2.w;
            float4 r3 = redQ[q * 64 + lane]; sq4.x += r3.x; sq4.y += r3.y; sq4.z += r3.z; sq4.w += r3.w;
        }
        cs4(zoutP + (size_t)p * Nout + c0, tov(sp));
        cs4(zoutQ + (size_t)p * Nout + c0, tov(sq4));
    }
}

// ---------- phase D side-work ----------
__device__ __forceinline__ void ph_finH1(int bb, const float* __restrict__ b1v,
                                         float* __restrict__ wsf, float* smem) {
    int tid = threadIdx.x;
    {
        int l4 = tid * 4;
        f32x4 p0 = cl4(wsf + OFF_Z1P + (size_t)((l4) >> 7) * 2048 + bb * 128 + (l4 & 127));
        f32x4 p1 = cl4(wsf + OFF_Z1P + (size_t)((l4 + 2048) >> 7) * 2048 + bb * 128 + ((l4 + 2048) & 127));
        vwait();
        *(f32x4*)(smem + l4) = p0;
        *(f32x4*)(smem + l4 + 2048) = p1;
    }
    __syncthreads();
    if (tid < 128) {
        int e = bb * 128 + tid;
        float s = 0.f;
#pragma unroll 8
        for (int pp = 0; pp < 32; ++pp) s += smem[pp * 128 + tid];
        float h = fmaxf(s + clf(b1v + e), 0.f);
        csf(wsf + OFF_H1F + e, h);
        csf(wsf + OFF_H1Q + e, DEC * h);
    }
}

__device__ __forceinline__ void ph_finH2(int bb, const float* __restrict__ b2v,
                                         float* __restrict__ wsf, float* smem) {
    int tid = threadIdx.x;
    {
        int l4 = tid * 4;
        f32x4 p0 = cl4(wsf + OFF_Z2P + (size_t)((l4) >> 7) * 2048 + bb * 128 + (l4 & 127));
        f32x4 p1 = cl4(wsf + OFF_Z2P + (size_t)((l4 + 2048) >> 7) * 2048 + bb * 128 + ((l4 + 2048) & 127));
        f32x4 q0 = cl4(wsf + OFF_Z2Q + (size_t)((l4) >> 7) * 2048 + bb * 128 + (l4 & 127));
        f32x4 q1 = cl4(wsf + OFF_Z2Q + (size_t)((l4 + 2048) >> 7) * 2048 + bb * 128 + ((l4 + 2048) & 127));
        vwait();
        *(f32x4*)(smem + l4) = p0; *(f32x4*)(smem + l4 + 2048) = p1;
        *(f32x4*)(smem + 4096 + l4) = q0; *(f32x4*)(smem + 4096 + l4 + 2048) = q1;
    }
    __syncthreads();
    if (tid < 128) {
        int e = bb * 128 + tid;
        float s = 0.f, sq = 0.f;
#pragma unroll 8
        for (int pp = 0; pp < 32; ++pp) { s += smem[pp * 128 + tid]; sq += smem[4096 + pp * 128 + tid]; }
        float bv = clf(b2v + e);
        csf(wsf + OFF_H2F + e, fmaxf(s + bv, 0.f));
        csf(wsf + OFF_H2Q + e, fmaxf(DEC * (sq + bv), 0.f));
    }
}

__device__ __forceinline__ void ph_normX(const float* __restrict__ xt,
                                         float* __restrict__ wsf, float* smem) {
    int tid = threadIdx.x;
    float v = 0.f;
    for (int e = tid; e < 768; e += 512) { float xv = xt[e]; v += xv * xv; }
    float s = block_reduce_512s(v, smem);
    if (tid == 0) csf(wsf + OFF_NSQ + 0, s);
}

// ||relu(Zred + bias)||^2 over 2048 cols; preserves the per-thread accumulation order
// of the old kernel (thread tid owns cols tid, tid+512, tid+1024, tid+1536 in order).
__device__ __forceinline__ void ph_normH(const float* __restrict__ zin,
                                         const float* __restrict__ bias, int idx,
                                         float* __restrict__ wsf, float* smem) {
    int tid = threadIdx.x;
    float* buf = smem;             // [32][256]
    float* red = smem + 8192;
    float v = 0.f;
    for (int c = 0; c < 8; ++c) {
        __syncthreads();
        {
            int l4 = tid * 4;
            f32x4 t0 = cl4(zin + (size_t)((l4) >> 8) * 2048 + c * 256 + (l4 & 255));
            f32x4 t1 = cl4(zin + (size_t)((l4 + 2048) >> 8) * 2048 + c * 256 + ((l4 + 2048) & 255));
            f32x4 t2 = cl4(zin + (size_t)((l4 + 4096) >> 8) * 2048 + c * 256 + ((l4 + 4096) & 255));
            f32x4 t3 = cl4(zin + (size_t)((l4 + 6144) >> 8) * 2048 + c * 256 + ((l4 + 6144) & 255));
            vwait();
            *(f32x4*)(buf + l4) = t0; *(f32x4*)(buf + l4 + 2048) = t1;
            *(f32x4*)(buf + l4 + 4096) = t2; *(f32x4*)(buf + l4 + 6144) = t3;
        }
        __syncthreads();
        int base = (c & 1) * 256;
        if ((tid & ~255) == base) {
            int jj = tid & 255;
            float s = 0.f;
#pragma unroll 8
            for (int pp = 0; pp < 32; ++pp) s += buf[pp * 256 + jj];
            float h = fmaxf(s + clf(bias + c * 256 + jj), 0.f);
            v += h * h;
        }
    }
    float s2 = block_reduce_512s(v, red);
    if (tid == 0) csf(wsf + OFF_NSQ + idx, s2);
}

// ---------- phase E: d4 finalize + h3 finalize + W4^T backward + ||d4||^2 ----------
// smem: bufP@0[4096] bufQ@4096[4096] dsP@8192[768] dsQ@8960[768] red@9728[512]
//       sqw@10240[8] h3f@10248[8] h3q@10256[8] h3bP@10264[256] h3bQ@10520[256]
__device__ __forceinline__ void ph_bwd4(const float* __restrict__ W4,
                                        const float* __restrict__ b3v,
                                        const float* __restrict__ b4v,
                                        const float* __restrict__ xt,
                                        float* __restrict__ wsf, float* smem) {
    int tid = threadIdx.x, b = blockIdx.x;
    float* bufP = smem;
    float* bufQ = smem + 4096;
    float* dsP  = smem + 8192;
    float* dsQ  = smem + 8960;
    float* red  = smem + 9728;
    float* sqw  = smem + 10240;
    float* h3f  = smem + 10248;
    float* h3q  = smem + 10256;
    float* h3bP = smem + 10264;
    float* h3bQ = smem + 10520;

    if (tid < 256) {
        int r = tid >> 5, pp = tid & 31;
        int j = b * 8 + r;
        h3bP[r * 32 + pp] = clf(wsf + OFF_Z3P + (size_t)pp * 2048 + j);
        h3bQ[r * 32 + pp] = clf(wsf + OFF_Z3Q + (size_t)pp * 2048 + j);
    }
    for (int c = 0; c < 6; ++c) {
        __syncthreads();
        {
            int l4 = tid * 4;
            f32x4 p0 = cl4(wsf + OFF_Z4P + (size_t)((l4) >> 7) * 768 + c * 128 + (l4 & 127));
            f32x4 p1 = cl4(wsf + OFF_Z4P + (size_t)((l4 + 2048) >> 7) * 768 + c * 128 + ((l4 + 2048) & 127));
            f32x4 q0 = cl4(wsf + OFF_Z4Q + (size_t)((l4) >> 7) * 768 + c * 128 + (l4 & 127));
            f32x4 q1 = cl4(wsf + OFF_Z4Q + (size_t)((l4 + 2048) >> 7) * 768 + c * 128 + ((l4 + 2048) & 127));
            vwait();
            *(f32x4*)(bufP + l4) = p0; *(f32x4*)(bufP + l4 + 2048) = p1;
            *(f32x4*)(bufQ + l4) = q0; *(f32x4*)(bufQ + l4 + 2048) = q1;
        }
        __syncthreads();
        if (tid < 128) {
            int e = c * 128 + tid;
            float s = 0.f, sq = 0.f;
#pragma unroll 8
            for (int pp = 0; pp < 32; ++pp) { s += bufP[pp * 128 + tid]; sq += bufQ[pp * 128 + tid]; }
            float bv = clf(b4v + e), tv = xt[e];
            dsP[e] = 2.f * ((s + bv) - tv) * (1.f / 768.f);
            dsQ[e] = 2.f * (DEC * (sq + bv) - tv) * (1.f / 768.f);
        }
    }
    __syncthreads();
    if (tid < 8) {
        int j = b * 8 + tid;
        float s = 0.f, sq = 0.f;
#pragma unroll 8
        for (int pp = 0; pp < 32; ++pp) { s += h3bP[tid * 32 + pp]; sq += h3bQ[tid * 32 + pp]; }
        float bv = clf(b3v + j);
        float hf = fmaxf(s + bv, 0.f);
        float hv = fmaxf(DEC * (sq + bv), 0.f);
        csf(wsf + OFF_H3F + j, hf);
        csf(wsf + OFF_H3Q + j, hv);
        h3f[tid] = hf; h3q[tid] = hv;
    }
    __syncthreads();
    if (b == 0) {
        for (int e = tid; e < 768; e += 512) { csf(wsf + OFF_D4F + e, dsP[e]); csf(wsf + OFF_D4Q + e, dsQ[e]); }
        float v = 0.f;
        for (int e = tid; e < 768; e += 512) { float d = dsP[e]; v += d * d; }
        float s = block_reduce_512s(v, red);
        if (tid == 0) csf(wsf + OFF_NSQ + 4, s);
    }
    int w = tid >> 6, lane = tid & 63;
    const float* row = W4 + (size_t)(b * 8 + w) * 768;
    f32x4 wv[3];
#pragma unroll
    for (int i = 0; i < 3; ++i) wv[i] = cl4(row + lane * 4 + i * 256);
    vwait();
    float apv = 0.f, aqv = 0.f;
#pragma unroll
    for (int i = 0; i < 3; ++i) {
        int k4 = lane * 4 + i * 256;
        apv += wv[i].x * dsP[k4] + wv[i].y * dsP[k4 + 1] + wv[i].z * dsP[k4 + 2] + wv[i].w * dsP[k4 + 3];
        aqv += wv[i].x * dsQ[k4] + wv[i].y * dsQ[k4 + 1] + wv[i].z * dsQ[k4 + 2] + wv[i].w * dsQ[k4 + 3];
    }
#pragma unroll
    for (int off = 32; off > 0; off >>= 1) { apv += __shfl_down(apv, off); aqv += __shfl_down(aqv, off); }
    if (lane == 0) {
        float dp = (h3f[w] > 0.f) ? apv : 0.f;
        float dq = (h3q[w] > 0.f) ? DEC * aqv : 0.f;
        csf(wsf + OFF_D3F + b * 8 + w, dp);
        csf(wsf + OFF_D3Q + b * 8 + w, dq);
        sqw[w] = dp * dp;
    }
    __syncthreads();
    if (tid == 0) {
        float s = 0.f;
#pragma unroll
        for (int q = 0; q < 8; ++q) s += sqw[q];
        csf(wsf + OFF_SL3 + b, s);
    }
}

// ---------- phases F/G: fused W^T backward, wave-per-row (K=2048) ----------
__device__ __forceinline__ void ph_bwd(int b, const float* __restrict__ W,
                                       const float* __restrict__ dinP,
                                       const float* __restrict__ dinQ,
                                       const float* __restrict__ hP,
                                       const float* __restrict__ hQ,
                                       float* __restrict__ doutP,
                                       float* __restrict__ doutQ,
                                       float* __restrict__ slot, float* smem) {
    int tid = threadIdx.x;
    float* dsP = smem;
    float* dsQ = smem + 2048;
    float* sqw = smem + 4096;
    {
        int l4 = tid * 4;
        f32x4 vP = cl4(dinP + l4);
        f32x4 vQ = cl4(dinQ + l4);
        vwait();
        *(f32x4*)(dsP + l4) = vP;
        *(f32x4*)(dsQ + l4) = vQ;
    }
    __syncthreads();
    int w = tid >> 6, lane = tid & 63;
    int j = b * 8 + w;
    const float* row = W + (size_t)j * 2048;
    float hPj = clf(hP + j), hQj = clf(hQ + j);
    f32x4 wv[8];
#pragma unroll
    for (int i = 0; i < 8; ++i) wv[i] = cl4(row + lane * 4 + i * 256);
    vwait();
    float ap = 0.f, aq = 0.f;
#pragma unroll
    for (int i = 0; i < 8; ++i) {
        int k4 = lane * 4 + i * 256;
        ap += wv[i].x * dsP[k4] + wv[i].y * dsP[k4 + 1] + wv[i].z * dsP[k4 + 2] + wv[i].w * dsP[k4 + 3];
        aq += wv[i].x * dsQ[k4] + wv[i].y * dsQ[k4 + 1] + wv[i].z * dsQ[k4 + 2] + wv[i].w * dsQ[k4 + 3];
    }
#pragma unroll
    for (int off = 32; off > 0; off >>= 1) { ap += __shfl_down(ap, off); aq += __shfl_down(aq, off); }
    if (lane == 0) {
        float dp = (hPj > 0.f) ? ap : 0.f;
        float dq = (hQj > 0.f) ? DEC * aq : 0.f;
        csf(doutP + j, dp);
        csf(doutQ + j, dq);
        sqw[w] = dp * dp;
    }
    __syncthreads();
    if (tid == 0) {
        float s = 0.f;
#pragma unroll
        for (int q = 0; q < 8; ++q) s += sqw[q];
        csf(slot + b, s);
    }
}

// ---------- epilogue: apply the LAST step's update ----------
__device__ __forceinline__ void ph_upd(int step, float* __restrict__ wsf,
                                       float* __restrict__ W1, float* __restrict__ b1,
                                       float* __restrict__ W2, float* __restrict__ b2,
                                       float* __restrict__ W3, float* __restrict__ b3,
                                       float* __restrict__ W4, float* __restrict__ b4,
                                       const float* __restrict__ xt, float* smem) {
    int tid = threadIdx.x, b = blockIdx.x;
    float* red = smem;
    float s3 = block_reduce_512s((tid < 256) ? clf(wsf + OFF_SL3 + tid) : 0.f, red);
    float s2 = block_reduce_512s((tid < 256) ? clf(wsf + OFF_SL2 + tid) : 0.f, red);
    float s1 = block_reduce_512s((tid < 256) ? clf(wsf + OFF_SL1 + tid) : 0.f, red);
    float* condp = smem + 512;
    if (tid == 0) {
        float nx  = sqrtf(clf(wsf + OFF_NSQ + 0));
        float nh1 = sqrtf(clf(wsf + OFF_NSQ + 1));
        float nh2 = sqrtf(clf(wsf + OFF_NSQ + 2));
        float nh3 = sqrtf(clf(wsf + OFF_NSQ + 3));
        float nd4 = sqrtf(clf(wsf + OFF_NSQ + 4));
        float nd3 = sqrtf(s3), nd2 = sqrtf(s2), nd1 = sqrtf(s1);
        float surprise = nx * nd1 + nd1 + nh1 * nd2 + nd2 + nh2 * nd3 + nd3 + nh3 * nd4 + nd4;
        float bufold = clf(wsf + OFF_BUF + (step & 1));
        float bufnew = (step == 0) ? surprise : (0.9f * bufold + 0.1f * surprise);
        csf(wsf + OFF_BUF + ((step + 1) & 1), bufnew);
        condp[0] = (bufnew > 0.1f) ? 1.f : 0.f;
    }
    __syncthreads();
    if (condp[0] == 0.f) return;

    int c = tid * 4;
    {   // W1: rows b*3..b*3+2
        f32x4 dv = cl4(wsf + OFF_D1Q + c);
        f32x4 w0 = cl4(W1 + (size_t)(b * 3 + 0) * 2048 + c);
        f32x4 w1v = cl4(W1 + (size_t)(b * 3 + 1) * 2048 + c);
        f32x4 w2v = cl4(W1 + (size_t)(b * 3 + 2) * 2048 + c);
        vwait();
        float u0 = LRC * xt[b * 3 + 0], u1 = LRC * xt[b * 3 + 1], u2 = LRC * xt[b * 3 + 2];
        rmw4(w0, u0, dv); rmw4(w1v, u1, dv); rmw4(w2v, u2, dv);
        cs4(W1 + (size_t)(b * 3 + 0) * 2048 + c, w0);
        cs4(W1 + (size_t)(b * 3 + 1) * 2048 + c, w1v);
        cs4(W1 + (size_t)(b * 3 + 2) * 2048 + c, w2v);
    }
    {   // W2
        f32x4 dv = cl4(wsf + OFF_D2Q + c);
        f32x4 wv[8];
        float us[8];
#pragma unroll
        for (int r = 0; r < 8; ++r) wv[r] = cl4(W2 + (size_t)(b * 8 + r) * 2048 + c);
#pragma unroll
        for (int r = 0; r < 8; ++r) us[r] = LRC * clf(wsf + OFF_H1Q + b * 8 + r);
        vwait();
#pragma unroll
        for (int r = 0; r < 8; ++r) {
            f32x4 t = wv[r];
            rmw4(t, us[r], dv);
            cs4(W2 + (size_t)(b * 8 + r) * 2048 + c, t);
        }
    }
    {   // W3
        f32x4 dv = cl4(wsf + OFF_D3Q + c);
        f32x4 wv[8];
        float us[8];
#pragma unroll
        for (int r = 0; r < 8; ++r) wv[r] = cl4(W3 + (size_t)(b * 8 + r) * 2048 + c);
#pragma unroll
        for (int r = 0; r < 8; ++r) us[r] = LRC * clf(wsf + OFF_H2Q + b * 8 + r);
        vwait();
#pragma unroll
        for (int r = 0; r < 8; ++r) {
            f32x4 t = wv[r];
            rmw4(t, us[r], dv);
            cs4(W3 + (size_t)(b * 8 + r) * 2048 + c, t);
        }
    }
    if (tid < 192) {   // W4: 2048x768
        f32x4 dv = cl4(wsf + OFF_D4Q + c);
        f32x4 wv[8];
        float us[8];
#pragma unroll
        for (int r = 0; r < 8; ++r) wv[r] = cl4(W4 + (size_t)(b * 8 + r) * 768 + c);
#pragma unroll
        for (int r = 0; r < 8; ++r) us[r] = LRC * clf(wsf + OFF_H3Q + b * 8 + r);
        vwait();
#pragma unroll
        for (int r = 0; r < 8; ++r) {
            f32x4 t = wv[r];
            rmw4(t, us[r], dv);
            cs4(W4 + (size_t)(b * 8 + r) * 768 + c, t);
        }
    }
    if (b == 0) {
        f32x4 dv = cl4(wsf + OFF_D1Q + c); f32x4 bv = cl4(b1 + c); vwait();
        rmw4(bv, LRC, dv); cs4(b1 + c, bv);
    } else if (b == 1) {
        f32x4 dv = cl4(wsf + OFF_D2Q + c); f32x4 bv = cl4(b2 + c); vwait();
        rmw4(bv, LRC, dv); cs4(b2 + c, bv);
    } else if (b == 2) {
        f32x4 dv = cl4(wsf + OFF_D3Q + c); f32x4 bv = cl4(b3 + c); vwait();
        rmw4(bv, LRC, dv); cs4(b3 + c, bv);
    } else if (b == 3 && tid < 192) {
        f32x4 dv = cl4(wsf + OFF_D4Q + c); f32x4 bv = cl4(b4 + c); vwait();
        rmw4(bv, LRC, dv); cs4(b4 + c, bv);
    }
}

// ---------- barrier-state init ----------
__global__ __launch_bounds__(1024) void k_zero(unsigned* __restrict__ bar) {
    bar[threadIdx.x] = 0u;
}

// ---------- the entire TTT scan as one persistent kernel ----------
__global__ __launch_bounds__(512) void k_scan(const float* __restrict__ x,
                                              float* __restrict__ W1, float* __restrict__ b1,
                                              float* __restrict__ W2, float* __restrict__ b2,
                                              float* __restrict__ W3, float* __restrict__ b3,
                                              float* __restrict__ W4, float* __restrict__ b4,
                                              float* __restrict__ wsf,
                                              const int* __restrict__ flag) {
    if (*flag == 0) return;          // uniform across grid
    __shared__ __align__(16) float smem[10784];
    unsigned* bar = (unsigned*)(wsf + OFF_HA);
    int b = blockIdx.x;
    for (int s = 0; s < 1024; ++s) {
        const float* xt = x + (size_t)s * 3072;
        const float* xprev = x + (size_t)(s > 0 ? s - 1 : 0) * 3072;
        ph_fwd1(s, xt, xprev, W1, b1, wsf, smem);
        gbar(bar);
        ph_fwd2(b, wsf + OFF_Z1P, nullptr, b1, W2, 2048, wsf + OFF_Z2P, wsf + OFF_Z2Q,
                wsf + OFF_H1Q, wsf + OFF_D2Q, b2, wsf, smem);
        gbar(bar);
        ph_fwd2(b, wsf + OFF_Z2P, wsf + OFF_Z2Q, b2, W3, 2048, wsf + OFF_Z3P, wsf + OFF_Z3Q,
                wsf + OFF_H2Q, wsf + OFF_D3Q, b3, wsf, smem);
        gbar(bar);
        if (b < 96) {
            ph_fwd2(b, wsf + OFF_Z3P, wsf + OFF_Z3Q, b3, W4, 768, wsf + OFF_Z4P, wsf + OFF_Z4Q,
                    wsf + OFF_H3Q, wsf + OFF_D4Q, b4, wsf, smem);
        } else if (b < 112) {
            ph_finH1(b - 96, b1, wsf, smem);
        } else if (b < 128) {
            ph_finH2(b - 112, b2, wsf, smem);
        } else if (b == 144) {
            ph_normX(xt, wsf, smem);
        } else if (b == 145) {
            ph_normH(wsf + OFF_Z1P, b1, 1, wsf, smem);
        } else if (b == 146) {
            ph_normH(wsf + OFF_Z2P, b2, 2, wsf, smem);
        } else if (b == 147) {
            ph_normH(wsf + OFF_Z3P, b3, 3, wsf, smem);
        }
        gbar(bar);
        ph_bwd4(W4, b3, b4, xt, wsf, smem);
        gbar(bar);
        ph_bwd(b, W3, wsf + OFF_D3F, wsf + OFF_D3Q, wsf + OFF_H2F, wsf + OFF_H2Q,
               wsf + OFF_D2F, wsf + OFF_D2Q, wsf + OFF_SL2, smem);
        gbar(bar);
        ph_bwd(b, W2, wsf + OFF_D2F, wsf + OFF_D2Q, wsf + OFF_H1F, wsf + OFF_H1Q,
               wsf + OFF_D1F, wsf + OFF_D1Q, wsf + OFF_SL1, smem);
        gbar(bar);
    }
    ph_upd(1023, wsf, W1, b1, W2, b2, W3, b3, W4, b4, x + (size_t)1023 * 3072, smem);
}

// ---------- final batch forward: fp32 tiled GEMM C = act(A@W + bias) ----------
__global__ __launch_bounds__(256) void k_gemm(const float* __restrict__ A,
                                              const float* __restrict__ W,
                                              const float* __restrict__ bias,
                                              float* __restrict__ C,
                                              int M, int N, int K, int do_relu) {
    __shared__ float sA[16][64];
    __shared__ float sB[16][128];
    int bn = blockIdx.x, bm = blockIdx.y;
    int m0 = bm * 64, n0 = bn * 128;
    int tid = threadIdx.x;
    int tx = tid & 31, ty = tid >> 5;
    float acc[8][4];
#pragma unroll
    for (int i = 0; i < 8; ++i)
#pragma unroll
        for (int j = 0; j < 4; ++j) acc[i][j] = 0.f;

    for (int kt = 0; kt < K; kt += 16) {
        {
            int r = tid >> 2, cc = (tid & 3) * 4;
            const float4 a4 = *(const float4*)(A + (size_t)(m0 + r) * K + kt + cc);
            sA[cc + 0][r] = a4.x; sA[cc + 1][r] = a4.y; sA[cc + 2][r] = a4.z; sA[cc + 3][r] = a4.w;
        }
        {
            int r = tid >> 5, cc = (tid & 31) * 4;
            *(float4*)(&sB[r][cc]) = *(const float4*)(W + (size_t)(kt + r) * N + n0 + cc);
            *(float4*)(&sB[r + 8][cc]) = *(const float4*)(W + (size_t)(kt + r + 8) * N + n0 + cc);
        }
        __syncthreads();
#pragma unroll
        for (int k = 0; k < 16; ++k) {
            float av[8];
#pragma unroll
            for (int i = 0; i < 8; ++i) av[i] = sA[k][ty * 8 + i];
            float bx = sB[k][tx * 4 + 0], by = sB[k][tx * 4 + 1];
            float bz = sB[k][tx * 4 + 2], bw = sB[k][tx * 4 + 3];
#pragma unroll
            for (int i = 0; i < 8; ++i) {
                acc[i][0] += av[i] * bx; acc[i][1] += av[i] * by;
                acc[i][2] += av[i] * bz; acc[i][3] += av[i] * bw;
            }
        }
        __syncthreads();
    }
    float bx = bias[n0 + tx * 4 + 0], by = bias[n0 + tx * 4 + 1];
    float bz = bias[n0 + tx * 4 + 2], bw = bias[n0 + tx * 4 + 3];
#pragma unroll
    for (int i = 0; i < 8; ++i) {
        int m = m0 + ty * 8 + i;
        float4 v;
        v.x = acc[i][0] + bx; v.y = acc[i][1] + by;
        v.z = acc[i][2] + bz; v.w = acc[i][3] + bw;
        if (do_relu) {
            v.x = fmaxf(v.x, 0.f); v.y = fmaxf(v.y, 0.f);
            v.z = fmaxf(v.z, 0.f); v.w = fmaxf(v.w, 0.f);
        }
        *(float4*)(C + (size_t)m * N + n0 + tx * 4) = v;
    }
}

__global__ __launch_bounds__(128) void k_colsum(const float* __restrict__ Y,
                                                float* __restrict__ out) {
    int c = blockIdx.x * 128 + threadIdx.x;
    int r0 = blockIdx.y * 128;
    float s = 0.f;
    for (int r = 0; r < 128; ++r) s += Y[(size_t)(r0 + r) * 768 + c];
    out[blockIdx.y * 768 + c] = s;
}

__global__ __launch_bounds__(768) void k_out(const float* __restrict__ msum,
                                             float* __restrict__ out) {
    int c = threadIdx.x;
    float s = 0.f;
#pragma unroll
    for (int i = 0; i < 32; ++i) s += msum[i * 768 + c];
    out[c] = s * (1.f / 4096.f);
}

extern "C" void kernel_launch(void* const* d_in, const int* in_sizes, int n_in,
                              void* d_out, int out_size, void* d_ws, size_t ws_size,
                              hipStream_t stream) {
    const float* x = (const float*)d_in[0];
    float* W1 = (float*)d_in[1];
    float* b1 = (float*)d_in[2];
    float* W2 = (float*)d_in[3];
    float* b2 = (float*)d_in[4];
    float* W3 = (float*)d_in[5];
    float* b3 = (float*)d_in[6];
    float* W4 = (float*)d_in[7];
    float* b4 = (float*)d_in[8];
    const int* flag = (const int*)d_in[9];
    float* wsf = (float*)d_ws;

    // barrier state lives in the HA region (unused until the final forward)
    unsigned* bar = (unsigned*)(wsf + OFF_HA);
    k_zero<<<1, 1024, 0, stream>>>(bar);

    // ---- entire 1024-step TTT scan: ONE persistent kernel, 7 light barriers/step ----
    k_scan<<<256, 512, 0, stream>>>(x, W1, b1, W2, b2, W3, b3, W4, b4, wsf, flag);

    // ---- final forward over all 4096 tokens, chunked by 1024, + mean ----
    float* HA = wsf + OFF_HA;
    float* HB = wsf + OFF_HB;
    for (int ch = 0; ch < 4; ++ch) {
        const float* Xc = x + (size_t)ch * 1024 * 768;
        k_gemm<<<dim3(16, 16), 256, 0, stream>>>(Xc, W1, b1, HA, 1024, 2048, 768, 1);
        k_gemm<<<dim3(16, 16), 256, 0, stream>>>(HA, W2, b2, HB, 1024, 2048, 2048, 1);
        k_gemm<<<dim3(16, 16), 256, 0, stream>>>(HB, W3, b3, HA, 1024, 2048, 2048, 1);
        k_gemm<<<dim3(6, 16), 256, 0, stream>>>(HA, W4, b4, HB, 1024, 768, 2048, 0);
        k_colsum<<<dim3(6, 8), 128, 0, stream>>>(HB, wsf + OFF_MSUM + (size_t)ch * 8 * 768);
    }
    k_out<<<1, 768, 0, stream>>>(wsf + OFF_MSUM, (float*)d_out);
}